// Round 2
// baseline (1044.576 us; speedup 1.0000x reference)
//
#include <hip/hip_runtime.h>
#include <stdint.h>

#define NN 50000
#define EE 800000
#define GG 128
#define DF 128
#define DE 256

typedef unsigned short u16;
typedef __bf16 bf16x8 __attribute__((ext_vector_type(8)));
typedef float f32x4 __attribute__((ext_vector_type(4)));

__device__ __forceinline__ float bf2f(u16 u) {
  union { unsigned int i; float f; } x; x.i = ((unsigned int)u) << 16; return x.f;
}
__device__ __forceinline__ u16 f2bf(float f) {
  union { float f; unsigned int i; } x; x.f = f;
  unsigned int i = x.i;
  return (u16)((i + 0x7fffu + ((i >> 16) & 1u)) >> 16);
}

// ---------------- dtype detection ----------------
// flags[0] = 1 if float tensors are f32 (else bf16); flags[1] = 1 if ints are int64
__global__ void detect_kernel(const u16* __restrict__ xr,
                              const unsigned* __restrict__ ei_words,
                              int* __restrict__ flags) {
  __shared__ int cnt;
  if (threadIdx.x == 0) cnt = 0;
  __syncthreads();
  int local = 0;
  for (int i = threadIdx.x; i < 131072; i += 256) {
    unsigned e = (xr[i] >> 7) & 0xFFu;   // bf16 exponent field
    if (e == 0xFFu) local++;             // NaN/inf pattern: impossible for N(0,1) bf16 data
  }
  atomicAdd(&cnt, local);
  __syncthreads();
  if (threadIdx.x == 0) flags[0] = (cnt > 0) ? 1 : 0;
  if (threadIdx.x < 64) {
    unsigned w = ei_words[threadIdx.x * 2 + 1];  // odd u32 words: 0 iff int64 storage
    unsigned long long nz = __ballot(w != 0u);
    if (threadIdx.x == 0) flags[1] = (nz == 0ull) ? 1 : 0;
  }
}

// ---------------- input normalization ----------------
struct ConvSeg { const void* src; u16* dst; int start_blk; int n; };
struct ConvArgs { ConvSeg s[13]; int nseg; };

__global__ void conv_many(ConvArgs A, const int* __restrict__ flags) {
  int f32f = flags[0];
  int b = blockIdx.x;
  for (int i = 0; i < A.nseg; i++) {
    int nb = (A.s[i].n + 255) >> 8;
    if (b >= A.s[i].start_blk && b < A.s[i].start_blk + nb) {
      int idx = ((b - A.s[i].start_blk) << 8) + threadIdx.x;
      if (idx < A.s[i].n) {
        u16 v = f32f ? f2bf(((const float*)A.s[i].src)[idx])
                     : ((const u16*)A.s[i].src)[idx];
        A.s[i].dst[idx] = v;
      }
      return;
    }
  }
}

__global__ void conv_idx(const void* __restrict__ ei, const void* __restrict__ batch,
                         int* __restrict__ src32, int* __restrict__ dst32,
                         int* __restrict__ batch32, const int* __restrict__ flags) {
  int i64 = flags[1];
  int i = blockIdx.x * blockDim.x + threadIdx.x;
  if (i < EE) {
    int s, d;
    if (i64) {
      s = (int)((const long long*)ei)[i];
      d = (int)((const long long*)ei)[EE + i];
    } else {
      s = ((const int*)ei)[i];
      d = ((const int*)ei)[EE + i];
    }
    src32[i] = min(max(s, 0), NN - 1);
    dst32[i] = min(max(d, 0), NN - 1);
  }
  if (i < NN) {
    int bv = i64 ? (int)((const long long*)batch)[i] : ((const int*)batch)[i];
    batch32[i] = min(max(bv, 0), GG - 1);
  }
}

// ---------------- CSR build ----------------
__global__ void hist_kernel(const int* __restrict__ dst, int* __restrict__ counts, int E) {
  int e = blockIdx.x * blockDim.x + threadIdx.x;
  if (e < E) atomicAdd(&counts[dst[e]], 1);
}

__global__ void scan_kernel(int* __restrict__ counts, int* __restrict__ row_ptr, int n) {
  __shared__ int sh[1024];
  __shared__ int base_sh;
  int tid = threadIdx.x;
  if (tid == 0) { base_sh = 0; row_ptr[0] = 0; }
  __syncthreads();
  for (int start = 0; start < n; start += 1024) {
    int i = start + tid;
    int x = (i < n) ? counts[i] : 0;
    sh[tid] = x;
    __syncthreads();
    for (int off = 1; off < 1024; off <<= 1) {
      int v = (tid >= off) ? sh[tid - off] : 0;
      __syncthreads();
      sh[tid] += v;
      __syncthreads();
    }
    int incl = sh[tid];
    int base = base_sh;
    __syncthreads();
    if (i < n) { row_ptr[i + 1] = base + incl; counts[i] = base + incl - x; }
    if (tid == 1023) base_sh = base + incl;
    __syncthreads();
  }
}

__global__ void scatter_kernel(const int* __restrict__ srcA, const int* __restrict__ dstA,
                               int* __restrict__ cursor, int* __restrict__ col_src, int E) {
  int e = blockIdx.x * blockDim.x + threadIdx.x;
  if (e < E) {
    int slot = atomicAdd(&cursor[dstA[e]], 1);
    col_src[slot] = srcA[e];
  }
}

__global__ void graph_start_kernel(const int* __restrict__ batch, int* __restrict__ gs, int n) {
  int g = threadIdx.x;
  if (g > GG) return;
  int lo = 0, hi = n;
  while (lo < hi) { int mid = (lo + hi) >> 1; if (batch[mid] < g) lo = mid + 1; else hi = mid; }
  gs[g] = lo;
}

// ---------------- weight prep: B^T layouts (dtype-flexible read) ----------------
__device__ __forceinline__ u16 ldw(const void* p, int idx, int f) {
  return f ? f2bf(((const float*)p)[idx]) : ((const u16*)p)[idx];
}

struct WPtrs {
  const void* Wl[4]; const void* Wr[4]; const void* Wm[4];
  u16* WcatT[4]; u16* WmT[4];
};

__global__ void prep_w_kernel(WPtrs P, const int* __restrict__ flags) {
  int f = flags[0];
  int seg = blockIdx.x >> 9;
  int idx = ((blockIdx.x & 511) << 8) + threadIdx.x;
  if (seg < 4) {
    int l = seg;
    int din = (l == 0) ? DF : DE;
    int K = 2 * din;
    if (idx < 256 * K) {
      int n = idx / K, k = idx - n * K;
      u16 v = (k < din) ? ldw(P.Wl[l], k * 256 + n, f) : ldw(P.Wr[l], (k - din) * 256 + n, f);
      P.WcatT[l][idx] = v;   // [n][k] row-major
    }
  } else {
    int l = seg - 4;
    if (idx < 256 * 256) {
      int n = idx >> 8, k = idx & 255;
      P.WmT[l][idx] = ldw(P.Wm[l], k * 256 + n, f);
    }
  }
}

// ---------------- per-node max aggregation (one wave per node) ----------------
template <int VPL>
__global__ __launch_bounds__(256) void segmax_kernel(
    const u16* __restrict__ feat, int fstride,
    const int* __restrict__ row_ptr, const int* __restrict__ col_src,
    u16* __restrict__ agg_out, int ostride,
    u16* __restrict__ copy_dst, int n) {
  int wave = blockIdx.x * 4 + (threadIdx.x >> 6);
  if (wave >= n) return;
  int lane = threadIdx.x & 63;
  int beg = row_ptr[wave], end = row_ptr[wave + 1];
  float m[VPL];
#pragma unroll
  for (int j = 0; j < VPL; j++) m[j] = -INFINITY;
  const u16* fb = feat + lane * VPL;
  int e = beg;
  for (; e + 2 <= end; e += 2) {
    int s0 = col_src[e], s1 = col_src[e + 1];
    const u16* p0 = fb + (long)s0 * fstride;
    const u16* p1 = fb + (long)s1 * fstride;
    if (VPL == 4) {
      ushort4 a = *(const ushort4*)p0;
      ushort4 b = *(const ushort4*)p1;
      m[0] = fmaxf(m[0], fmaxf(bf2f(a.x), bf2f(b.x)));
      m[1] = fmaxf(m[1], fmaxf(bf2f(a.y), bf2f(b.y)));
      m[2] = fmaxf(m[2], fmaxf(bf2f(a.z), bf2f(b.z)));
      m[3] = fmaxf(m[3], fmaxf(bf2f(a.w), bf2f(b.w)));
    } else {
      ushort2 a = *(const ushort2*)p0;
      ushort2 b = *(const ushort2*)p1;
      m[0] = fmaxf(m[0], fmaxf(bf2f(a.x), bf2f(b.x)));
      m[1] = fmaxf(m[1], fmaxf(bf2f(a.y), bf2f(b.y)));
    }
  }
  if (e < end) {
    int s0 = col_src[e];
    const u16* p0 = fb + (long)s0 * fstride;
    if (VPL == 4) {
      ushort4 a = *(const ushort4*)p0;
      m[0] = fmaxf(m[0], bf2f(a.x)); m[1] = fmaxf(m[1], bf2f(a.y));
      m[2] = fmaxf(m[2], bf2f(a.z)); m[3] = fmaxf(m[3], bf2f(a.w));
    } else {
      ushort2 a = *(const ushort2*)p0;
      m[0] = fmaxf(m[0], bf2f(a.x)); m[1] = fmaxf(m[1], bf2f(a.y));
    }
  }
  if (beg == end) {
#pragma unroll
    for (int j = 0; j < VPL; j++) m[j] = 0.f;   // empty segment -> 0 (PyG convention)
  }
  u16* op = agg_out + (long)wave * ostride + lane * VPL;
  if (VPL == 4) {
    ushort4 o; o.x = f2bf(m[0]); o.y = f2bf(m[1]); o.z = f2bf(m[2]); o.w = f2bf(m[3]);
    *(ushort4*)op = o;
  } else {
    ushort2 o; o.x = f2bf(m[0]); o.y = f2bf(m[1]);
    *(ushort2*)op = o;
  }
  if (copy_dst) {
    const u16* xp = feat + (long)wave * fstride + lane * VPL;
    u16* cp = copy_dst + (long)wave * ostride + lane * VPL;
    if (VPL == 4) *(ushort4*)cp = *(const ushort4*)xp;
    else          *(ushort2*)cp = *(const ushort2*)xp;
  }
}

// ---------------- MFMA GEMM: C[M,256] = op(A[M,K] @ B[K,256] + bias) ----------------
// BT is B^T [256][K]; 128x128 tile, 4 waves, 4x4 16x16x32 frags; register->LDS staging
__global__ __launch_bounds__(256) void gemm_kernel(
    const u16* __restrict__ A, int lda, int K,
    const u16* __restrict__ BT,
    const u16* __restrict__ bias,
    u16* __restrict__ C, int ldc,
    int M, int relu_flag) {
  __shared__ u16 lsA[128 * 32];
  __shared__ u16 lsB[128 * 32];
  int tid = threadIdx.x;
  int lane = tid & 63, w = tid >> 6;
  int bm = blockIdx.x >> 1, bn = blockIdx.x & 1;
  int wm = (w & 1) << 6, wn = (w >> 1) << 6;
  int ln15 = lane & 15, quad = lane >> 4;

  f32x4 acc[4][4] = {};

  // staging: thread t covers 8 u16 at linear offset t*8 (pass0: rows 0..63) and +2048 (rows 64..127)
  int r0 = tid >> 2;
  int kc = (tid & 3) << 3;
  int am0 = min(bm * 128 + r0, M - 1);
  int am1 = min(bm * 128 + r0 + 64, M - 1);
  const u16* gA0 = A + (long)am0 * lda + kc;
  const u16* gA1 = A + (long)am1 * lda + kc;
  const u16* gB0 = BT + (long)(bn * 128 + r0) * K + kc;
  const u16* gB1 = BT + (long)(bn * 128 + r0 + 64) * K + kc;
  u16* sA0 = lsA + r0 * 32 + kc;  u16* sA1 = sA0 + 64 * 32;
  u16* sB0 = lsB + r0 * 32 + kc;  u16* sB1 = sB0 + 64 * 32;

  for (int k0 = 0; k0 < K; k0 += 32) {
    bf16x8 a0 = *(const bf16x8*)(gA0 + k0);
    bf16x8 a1 = *(const bf16x8*)(gA1 + k0);
    bf16x8 b0 = *(const bf16x8*)(gB0 + k0);
    bf16x8 b1 = *(const bf16x8*)(gB1 + k0);
    __syncthreads();   // previous iter's readers done before overwrite
    *(bf16x8*)sA0 = a0; *(bf16x8*)sA1 = a1;
    *(bf16x8*)sB0 = b0; *(bf16x8*)sB1 = b1;
    __syncthreads();
    bf16x8 af[4], bfr[4];
#pragma unroll
    for (int t = 0; t < 4; t++) {
      af[t]  = *(const bf16x8*)(lsA + (wm + t * 16 + ln15) * 32 + quad * 8);
      bfr[t] = *(const bf16x8*)(lsB + (wn + t * 16 + ln15) * 32 + quad * 8);
    }
#pragma unroll
    for (int mt = 0; mt < 4; mt++)
#pragma unroll
      for (int nt = 0; nt < 4; nt++)
        acc[mt][nt] = __builtin_amdgcn_mfma_f32_16x16x32_bf16(af[mt], bfr[nt], acc[mt][nt], 0, 0, 0);
  }

  float bv[4];
#pragma unroll
  for (int nt = 0; nt < 4; nt++)
    bv[nt] = bf2f(bias[bn * 128 + wn + nt * 16 + ln15]);

#pragma unroll
  for (int mt = 0; mt < 4; mt++) {
    int row0 = bm * 128 + wm + mt * 16 + quad * 4;
#pragma unroll
    for (int r = 0; r < 4; r++) {
      int row = row0 + r;
      if (row < M) {
#pragma unroll
        for (int nt = 0; nt < 4; nt++) {
          float v = acc[mt][nt][r] + bv[nt];
          if (relu_flag) v = fmaxf(v, 0.f);
          C[(long)row * ldc + bn * 128 + wn + nt * 16 + ln15] = f2bf(v);
        }
      }
    }
  }
}

// ---------------- per-layer global max pool into g_pool[:, l*256:] ----------------
__global__ void pool_kernel(const u16* __restrict__ h, const int* __restrict__ gs,
                            float* __restrict__ g_pool, int l) {
  int g = blockIdx.x;
  int c = threadIdx.x & 255, ty = threadIdx.x >> 8;
  int beg = gs[g], end = gs[g + 1];
  float m = -INFINITY;
  for (int n = beg + ty; n < end; n += 4)
    m = fmaxf(m, bf2f(h[(long)n * 512 + c]));
  __shared__ float red[4][256];
  red[ty][c] = m;
  __syncthreads();
  if (ty == 0) {
    m = fmaxf(fmaxf(red[0][c], red[1][c]), fmaxf(red[2][c], red[3][c]));
    if (!(m > -INFINITY)) m = 0.f;
    g_pool[g * 1024 + l * 256 + c] = m;
  }
}

// ---------------- head (output dtype branches on flags[0]) ----------------
__global__ void fc1_kernel(const float* __restrict__ gp, const u16* __restrict__ W,
                           const u16* __restrict__ b, float* __restrict__ last_f,
                           void* __restrict__ outbuf, const int* __restrict__ flags) {
  int g = blockIdx.x, c = threadIdx.x;
  float acc = bf2f(b[c]);
  const float* gr = gp + g * 1024;
#pragma unroll 4
  for (int k = 0; k < 1024; k++)
    acc += gr[k] * bf2f(W[k * 256 + c]);
  acc = fmaxf(acc, 0.f);
  last_f[g * 256 + c] = acc;
  if (flags[0]) ((float*)outbuf)[4608 + g * 256 + c] = acc;
  else          ((u16*)outbuf)[4608 + g * 256 + c] = f2bf(acc);
}

__global__ void fc2_kernel(const float* __restrict__ last, const u16* __restrict__ W,
                           const u16* __restrict__ b, void* __restrict__ outbuf,
                           const int* __restrict__ flags) {
  int g = blockIdx.x, t = threadIdx.x;
  __shared__ float sv[18];
  __shared__ float sred[2];
  if (t < 18) {
    float acc = bf2f(b[t]);
    const float* lr = last + g * 256;
    for (int k = 0; k < 256; k++)
      acc += lr[k] * bf2f(W[k * 18 + t]);
    sv[t] = acc;
  }
  __syncthreads();
  if (t == 0) {
    float mx = sv[0];
    for (int i = 1; i < 18; i++) mx = fmaxf(mx, sv[i]);
    float s = 0.f;
    for (int i = 0; i < 18; i++) s += expf(sv[i] - mx);
    sred[0] = mx; sred[1] = logf(s);
  }
  __syncthreads();
  if (t < 18) {
    float raw = sv[t];
    float lsm = sv[t] - sred[0] - sred[1];
    if (flags[0]) {
      ((float*)outbuf)[g * 18 + t] = lsm;
      ((float*)outbuf)[2304 + g * 18 + t] = raw;
    } else {
      ((u16*)outbuf)[g * 18 + t] = f2bf(lsm);
      ((u16*)outbuf)[2304 + g * 18 + t] = f2bf(raw);
    }
  }
}

extern "C" void kernel_launch(void* const* d_in, const int* in_sizes, int n_in,
                              void* d_out, int out_size, void* d_ws, size_t ws_size,
                              hipStream_t stream) {
  (void)in_sizes; (void)n_in; (void)out_size; (void)ws_size;
  const void* x = d_in[0];
  const void* ei = d_in[1];
  const void* batch = d_in[2];
  const void *Wl[4], *bl[4], *Wr[4], *Wm[4], *bm[4];
  for (int l = 0; l < 4; l++) {
    Wl[l] = d_in[3 + l * 5 + 0];
    bl[l] = d_in[3 + l * 5 + 1];
    Wr[l] = d_in[3 + l * 5 + 2];
    Wm[l] = d_in[3 + l * 5 + 3];
    bm[l] = d_in[3 + l * 5 + 4];
  }
  const void* fc1W = d_in[23];
  const void* fc1b = d_in[24];
  const void* fc2W = d_in[25];
  const void* fc2b = d_in[26];

  char* ws = (char*)d_ws;
  size_t off = 0;
  auto alloc = [&](size_t bytes) -> void* {
    void* p = ws + off;
    off = (off + bytes + 255) & ~(size_t)255;
    return p;
  };
  int* flags   = (int*)alloc(16);
  int* row_ptr = (int*)alloc((NN + 1) * sizeof(int));
  int* cursor  = (int*)alloc(NN * sizeof(int));
  int* col_src = (int*)alloc((size_t)EE * sizeof(int));
  int* src32   = (int*)alloc((size_t)EE * sizeof(int));
  int* dst32   = (int*)alloc((size_t)EE * sizeof(int));
  int* batch32 = (int*)alloc(NN * sizeof(int));
  int* gs      = (int*)alloc((GG + 1) * sizeof(int));
  u16* WcatT[4]; for (int l = 0; l < 4; l++) WcatT[l] = (u16*)alloc(256 * 512 * 2);
  u16* WmT[4];   for (int l = 0; l < 4; l++) WmT[l]   = (u16*)alloc(256 * 256 * 2);
  u16* bl_bf[4]; for (int l = 0; l < 4; l++) bl_bf[l] = (u16*)alloc(256 * 2);
  u16* bm_bf[4]; for (int l = 0; l < 4; l++) bm_bf[l] = (u16*)alloc(256 * 2);
  u16* fc1W_bf = (u16*)alloc(1024 * 256 * 2);
  u16* fc1b_bf = (u16*)alloc(256 * 2);
  u16* fc2W_bf = (u16*)alloc(256 * 18 * 2);
  u16* fc2b_bf = (u16*)alloc(18 * 2);
  u16* x_bf    = (u16*)alloc((size_t)NN * DF * 2);
  u16* Acat    = (u16*)alloc((size_t)NN * 512 * 2);  // [agg(256) | h(256)] per node
  u16* tmp     = (u16*)alloc((size_t)NN * 256 * 2);
  float* gpool = (float*)alloc(GG * 1024 * sizeof(float));
  float* lastf = (float*)alloc(GG * 256 * sizeof(float));

  detect_kernel<<<1, 256, 0, stream>>>((const u16*)x, (const unsigned*)ei, flags);

  ConvArgs CA; int blk = 0; int si = 0;
  auto addseg = [&](const void* s, u16* d, int n) {
    CA.s[si].src = s; CA.s[si].dst = d; CA.s[si].start_blk = blk; CA.s[si].n = n;
    blk += (n + 255) / 256; si++;
  };
  addseg(x, x_bf, NN * DF);
  addseg(fc1W, fc1W_bf, 1024 * 256);
  addseg(fc2W, fc2W_bf, 256 * 18);
  for (int l = 0; l < 4; l++) addseg(bl[l], bl_bf[l], 256);
  for (int l = 0; l < 4; l++) addseg(bm[l], bm_bf[l], 256);
  addseg(fc1b, fc1b_bf, 256);
  addseg(fc2b, fc2b_bf, 18);
  CA.nseg = si;
  conv_many<<<blk, 256, 0, stream>>>(CA, flags);
  conv_idx<<<(EE + 255) / 256, 256, 0, stream>>>(ei, batch, src32, dst32, batch32, flags);

  WPtrs P;
  for (int l = 0; l < 4; l++) {
    P.Wl[l] = Wl[l]; P.Wr[l] = Wr[l]; P.Wm[l] = Wm[l];
    P.WcatT[l] = WcatT[l]; P.WmT[l] = WmT[l];
  }
  prep_w_kernel<<<4096, 256, 0, stream>>>(P, flags);

  hipMemsetAsync(cursor, 0, NN * sizeof(int), stream);
  hist_kernel<<<(EE + 255) / 256, 256, 0, stream>>>(dst32, cursor, EE);
  scan_kernel<<<1, 1024, 0, stream>>>(cursor, row_ptr, NN);
  scatter_kernel<<<(EE + 255) / 256, 256, 0, stream>>>(src32, dst32, cursor, col_src, EE);
  graph_start_kernel<<<1, 256, 0, stream>>>(batch32, gs, NN);

  int segblocks = (NN + 3) / 4;
  int gemmgrid = ((NN + 127) / 128) * 2;

  for (int l = 0; l < 4; l++) {
    if (l == 0) {
      segmax_kernel<2><<<segblocks, 256, 0, stream>>>(x_bf, DF, row_ptr, col_src,
                                                      Acat, 512, Acat + DF, NN);
    } else {
      segmax_kernel<4><<<segblocks, 256, 0, stream>>>(Acat + 256, 512, row_ptr, col_src,
                                                      Acat, 512, (u16*)nullptr, NN);
    }
    int K = (l == 0) ? 256 : 512;
    gemm_kernel<<<gemmgrid, 256, 0, stream>>>(Acat, 512, K, WcatT[l], bl_bf[l], tmp, 256, NN, 0);
    gemm_kernel<<<gemmgrid, 256, 0, stream>>>(tmp, 256, 256, WmT[l], bm_bf[l], Acat + 256, 512, NN, 1);
    pool_kernel<<<GG, 1024, 0, stream>>>(Acat + 256, gs, gpool, l);
  }

  fc1_kernel<<<GG, 256, 0, stream>>>(gpool, fc1W_bf, fc1b_bf, lastf, d_out, flags);
  fc2_kernel<<<GG, 64, 0, stream>>>(lastf, fc2W_bf, fc2b_bf, d_out, flags);
}

// Round 3
// 855.598 us; speedup vs baseline: 1.2209x; 1.2209x over previous
//
#include <hip/hip_runtime.h>
#include <stdint.h>

#define NN 50000
#define EE 800000
#define GG 128
#define DF 128
#define DE 256
#define NCHUNK ((NN + 255) / 256)   // 196

typedef unsigned short u16;
typedef __bf16 bf16x8 __attribute__((ext_vector_type(8)));
typedef float f32x4 __attribute__((ext_vector_type(4)));

__device__ __forceinline__ float bf2f(u16 u) {
  union { unsigned int i; float f; } x; x.i = ((unsigned int)u) << 16; return x.f;
}
__device__ __forceinline__ u16 f2bf(float f) {
  union { float f; unsigned int i; } x; x.f = f;
  unsigned int i = x.i;
  return (u16)((i + 0x7fffu + ((i >> 16) & 1u)) >> 16);
}

// ---------------- dtype detection (parallel) ----------------
// flags[0]=1 -> float tensors stored f32 (else bf16)
// flags[1]=1 -> found nonzero odd u32 word in edge_index => int32 storage; ==0 => int64
__global__ void detect_kernel(const u16* __restrict__ xr,
                              const unsigned* __restrict__ ei_words,
                              int* __restrict__ flags) {
  int i = blockIdx.x * 256 + threadIdx.x;        // 256 blocks x 256 threads, 2 elems each
  int found = 0;
  u16 a = xr[i * 2], b = xr[i * 2 + 1];
  if (((a >> 7) & 0xFFu) == 0xFFu) found = 1;    // bf16 exp=0xFF: impossible for N(0,1) bf16
  if (((b >> 7) & 0xFFu) == 0xFFu) found = 1;
  if (__ballot(found)) {
    if ((threadIdx.x & 63) == 0) atomicOr(&flags[0], 1);
  }
  if (blockIdx.x == 0 && threadIdx.x < 64) {
    unsigned w = ei_words[threadIdx.x * 2 + 1];
    if (__ballot(w != 0u)) {
      if (threadIdx.x == 0) atomicOr(&flags[1], 1);
    }
  }
}

// ---------------- input normalization ----------------
struct ConvSeg { const void* src; u16* dst; int start_blk; int n; };
struct ConvArgs { ConvSeg s[13]; int nseg; };

__global__ void conv_many(ConvArgs A, const int* __restrict__ flags) {
  int f32f = flags[0];
  int b = blockIdx.x;
  for (int i = 0; i < A.nseg; i++) {
    int nb = (A.s[i].n + 255) >> 8;
    if (b >= A.s[i].start_blk && b < A.s[i].start_blk + nb) {
      int idx = ((b - A.s[i].start_blk) << 8) + threadIdx.x;
      if (idx < A.s[i].n) {
        u16 v = f32f ? f2bf(((const float*)A.s[i].src)[idx])
                     : ((const u16*)A.s[i].src)[idx];
        A.s[i].dst[idx] = v;
      }
      return;
    }
  }
}

__global__ void conv_idx(const void* __restrict__ ei, const void* __restrict__ batch,
                         int* __restrict__ src32, int* __restrict__ dst32,
                         int* __restrict__ batch32, const int* __restrict__ flags) {
  int i64 = (flags[1] == 0);
  int i = blockIdx.x * blockDim.x + threadIdx.x;
  if (i < EE) {
    int s, d;
    if (i64) {
      s = (int)((const long long*)ei)[i];
      d = (int)((const long long*)ei)[EE + i];
    } else {
      s = ((const int*)ei)[i];
      d = ((const int*)ei)[EE + i];
    }
    src32[i] = min(max(s, 0), NN - 1);
    dst32[i] = min(max(d, 0), NN - 1);
  }
  if (i < NN) {
    int bv = i64 ? (int)((const long long*)batch)[i] : ((const int*)batch)[i];
    batch32[i] = min(max(bv, 0), GG - 1);
  }
}

// ---------------- CSR build ----------------
__global__ void hist_kernel(const int* __restrict__ dst, int* __restrict__ counts, int E) {
  int e = blockIdx.x * blockDim.x + threadIdx.x;
  if (e < E) atomicAdd(&counts[dst[e]], 1);
}

// per-256-chunk sums
__global__ void chunk_sum_kernel(const int* __restrict__ counts, int* __restrict__ partial, int n) {
  __shared__ int sh[256];
  int i = blockIdx.x * 256 + threadIdx.x;
  sh[threadIdx.x] = (i < n) ? counts[i] : 0;
  __syncthreads();
  for (int off = 128; off > 0; off >>= 1) {
    if (threadIdx.x < off) sh[threadIdx.x] += sh[threadIdx.x + off];
    __syncthreads();
  }
  if (threadIdx.x == 0) partial[blockIdx.x] = sh[0];
}

// exclusive scan of NCHUNK partials (single small block)
__global__ void scan_partial_kernel(int* __restrict__ partial, int np) {
  __shared__ int sh[256];
  int tid = threadIdx.x;
  int x = (tid < np) ? partial[tid] : 0;
  sh[tid] = x;
  __syncthreads();
  for (int off = 1; off < 256; off <<= 1) {
    int v = (tid >= off) ? sh[tid - off] : 0;
    __syncthreads();
    sh[tid] += v;
    __syncthreads();
  }
  if (tid < np) partial[tid] = sh[tid] - x;   // exclusive
}

// per-chunk in-block scan + base offset; writes row_ptr and cursor
__global__ void write_rowptr_kernel(int* __restrict__ counts, const int* __restrict__ partial,
                                    int* __restrict__ row_ptr, int n) {
  __shared__ int sh[256];
  int tid = threadIdx.x;
  int i = blockIdx.x * 256 + tid;
  int x = (i < n) ? counts[i] : 0;
  sh[tid] = x;
  __syncthreads();
  for (int off = 1; off < 256; off <<= 1) {
    int v = (tid >= off) ? sh[tid - off] : 0;
    __syncthreads();
    sh[tid] += v;
    __syncthreads();
  }
  int base = partial[blockIdx.x];
  if (i < n) {
    row_ptr[i + 1] = base + sh[tid];
    counts[i] = base + sh[tid] - x;   // cursor = row start
  }
  if (i == 0) row_ptr[0] = 0;
}

__global__ void scatter_kernel(const int* __restrict__ srcA, const int* __restrict__ dstA,
                               int* __restrict__ cursor, int* __restrict__ col_src, int E) {
  int e = blockIdx.x * blockDim.x + threadIdx.x;
  if (e < E) {
    int slot = atomicAdd(&cursor[dstA[e]], 1);
    col_src[slot] = srcA[e];
  }
}

__global__ void graph_start_kernel(const int* __restrict__ batch, int* __restrict__ gs, int n) {
  int g = threadIdx.x;
  if (g > GG) return;
  int lo = 0, hi = n;
  while (lo < hi) { int mid = (lo + hi) >> 1; if (batch[mid] < g) lo = mid + 1; else hi = mid; }
  gs[g] = lo;
}

// ---------------- weight prep: B^T layouts (dtype-flexible read) ----------------
__device__ __forceinline__ u16 ldw(const void* p, int idx, int f) {
  return f ? f2bf(((const float*)p)[idx]) : ((const u16*)p)[idx];
}

struct WPtrs {
  const void* Wl[4]; const void* Wr[4]; const void* Wm[4];
  u16* WcatT[4]; u16* WmT[4];
};

__global__ void prep_w_kernel(WPtrs P, const int* __restrict__ flags) {
  int f = flags[0];
  int seg = blockIdx.x >> 9;
  int idx = ((blockIdx.x & 511) << 8) + threadIdx.x;
  if (seg < 4) {
    int l = seg;
    int din = (l == 0) ? DF : DE;
    int K = 2 * din;
    if (idx < 256 * K) {
      int n = idx / K, k = idx - n * K;
      u16 v = (k < din) ? ldw(P.Wl[l], k * 256 + n, f) : ldw(P.Wr[l], (k - din) * 256 + n, f);
      P.WcatT[l][idx] = v;   // [n][k] row-major
    }
  } else {
    int l = seg - 4;
    if (idx < 256 * 256) {
      int n = idx >> 8, k = idx & 255;
      P.WmT[l][idx] = ldw(P.Wm[l], k * 256 + n, f);
    }
  }
}

// ---------------- per-node max aggregation (one wave per node) ----------------
template <int VPL>
__global__ __launch_bounds__(256) void segmax_kernel(
    const u16* __restrict__ feat, int fstride,
    const int* __restrict__ row_ptr, const int* __restrict__ col_src,
    u16* __restrict__ agg_out, int ostride,
    u16* __restrict__ copy_dst, int n) {
  int wave = blockIdx.x * 4 + (threadIdx.x >> 6);
  if (wave >= n) return;
  int lane = threadIdx.x & 63;
  int beg = row_ptr[wave], end = row_ptr[wave + 1];
  float m[VPL];
#pragma unroll
  for (int j = 0; j < VPL; j++) m[j] = -INFINITY;
  const u16* fb = feat + lane * VPL;
  int e = beg;
  for (; e + 2 <= end; e += 2) {
    int s0 = col_src[e], s1 = col_src[e + 1];
    const u16* p0 = fb + (long)s0 * fstride;
    const u16* p1 = fb + (long)s1 * fstride;
    if (VPL == 4) {
      ushort4 a = *(const ushort4*)p0;
      ushort4 b = *(const ushort4*)p1;
      m[0] = fmaxf(m[0], fmaxf(bf2f(a.x), bf2f(b.x)));
      m[1] = fmaxf(m[1], fmaxf(bf2f(a.y), bf2f(b.y)));
      m[2] = fmaxf(m[2], fmaxf(bf2f(a.z), bf2f(b.z)));
      m[3] = fmaxf(m[3], fmaxf(bf2f(a.w), bf2f(b.w)));
    } else {
      ushort2 a = *(const ushort2*)p0;
      ushort2 b = *(const ushort2*)p1;
      m[0] = fmaxf(m[0], fmaxf(bf2f(a.x), bf2f(b.x)));
      m[1] = fmaxf(m[1], fmaxf(bf2f(a.y), bf2f(b.y)));
    }
  }
  if (e < end) {
    int s0 = col_src[e];
    const u16* p0 = fb + (long)s0 * fstride;
    if (VPL == 4) {
      ushort4 a = *(const ushort4*)p0;
      m[0] = fmaxf(m[0], bf2f(a.x)); m[1] = fmaxf(m[1], bf2f(a.y));
      m[2] = fmaxf(m[2], bf2f(a.z)); m[3] = fmaxf(m[3], bf2f(a.w));
    } else {
      ushort2 a = *(const ushort2*)p0;
      m[0] = fmaxf(m[0], bf2f(a.x)); m[1] = fmaxf(m[1], bf2f(a.y));
    }
  }
  if (beg == end) {
#pragma unroll
    for (int j = 0; j < VPL; j++) m[j] = 0.f;   // empty segment -> 0 (PyG convention)
  }
  u16* op = agg_out + (long)wave * ostride + lane * VPL;
  if (VPL == 4) {
    ushort4 o; o.x = f2bf(m[0]); o.y = f2bf(m[1]); o.z = f2bf(m[2]); o.w = f2bf(m[3]);
    *(ushort4*)op = o;
  } else {
    ushort2 o; o.x = f2bf(m[0]); o.y = f2bf(m[1]);
    *(ushort2*)op = o;
  }
  if (copy_dst) {
    const u16* xp = feat + (long)wave * fstride + lane * VPL;
    u16* cp = copy_dst + (long)wave * ostride + lane * VPL;
    if (VPL == 4) *(ushort4*)cp = *(const ushort4*)xp;
    else          *(ushort2*)cp = *(const ushort2*)xp;
  }
}

// ---------------- MFMA GEMM: C[M,256] = op(A[M,K] @ B[K,256] + bias) ----------------
__global__ __launch_bounds__(256) void gemm_kernel(
    const u16* __restrict__ A, int lda, int K,
    const u16* __restrict__ BT,
    const u16* __restrict__ bias,
    u16* __restrict__ C, int ldc,
    int M, int relu_flag) {
  __shared__ u16 lsA[128 * 32];
  __shared__ u16 lsB[128 * 32];
  int tid = threadIdx.x;
  int lane = tid & 63, w = tid >> 6;
  int bm = blockIdx.x >> 1, bn = blockIdx.x & 1;
  int wm = (w & 1) << 6, wn = (w >> 1) << 6;
  int ln15 = lane & 15, quad = lane >> 4;

  f32x4 acc[4][4] = {};

  int r0 = tid >> 2;
  int kc = (tid & 3) << 3;
  int am0 = min(bm * 128 + r0, M - 1);
  int am1 = min(bm * 128 + r0 + 64, M - 1);
  const u16* gA0 = A + (long)am0 * lda + kc;
  const u16* gA1 = A + (long)am1 * lda + kc;
  const u16* gB0 = BT + (long)(bn * 128 + r0) * K + kc;
  const u16* gB1 = BT + (long)(bn * 128 + r0 + 64) * K + kc;
  u16* sA0 = lsA + r0 * 32 + kc;  u16* sA1 = sA0 + 64 * 32;
  u16* sB0 = lsB + r0 * 32 + kc;  u16* sB1 = sB0 + 64 * 32;

  for (int k0 = 0; k0 < K; k0 += 32) {
    bf16x8 a0 = *(const bf16x8*)(gA0 + k0);
    bf16x8 a1 = *(const bf16x8*)(gA1 + k0);
    bf16x8 b0 = *(const bf16x8*)(gB0 + k0);
    bf16x8 b1 = *(const bf16x8*)(gB1 + k0);
    __syncthreads();
    *(bf16x8*)sA0 = a0; *(bf16x8*)sA1 = a1;
    *(bf16x8*)sB0 = b0; *(bf16x8*)sB1 = b1;
    __syncthreads();
    bf16x8 af[4], bfr[4];
#pragma unroll
    for (int t = 0; t < 4; t++) {
      af[t]  = *(const bf16x8*)(lsA + (wm + t * 16 + ln15) * 32 + quad * 8);
      bfr[t] = *(const bf16x8*)(lsB + (wn + t * 16 + ln15) * 32 + quad * 8);
    }
#pragma unroll
    for (int mt = 0; mt < 4; mt++)
#pragma unroll
      for (int nt = 0; nt < 4; nt++)
        acc[mt][nt] = __builtin_amdgcn_mfma_f32_16x16x32_bf16(af[mt], bfr[nt], acc[mt][nt], 0, 0, 0);
  }

  float bv[4];
#pragma unroll
  for (int nt = 0; nt < 4; nt++)
    bv[nt] = bf2f(bias[bn * 128 + wn + nt * 16 + ln15]);

#pragma unroll
  for (int mt = 0; mt < 4; mt++) {
    int row0 = bm * 128 + wm + mt * 16 + quad * 4;
#pragma unroll
    for (int r = 0; r < 4; r++) {
      int row = row0 + r;
      if (row < M) {
#pragma unroll
        for (int nt = 0; nt < 4; nt++) {
          float v = acc[mt][nt][r] + bv[nt];
          if (relu_flag) v = fmaxf(v, 0.f);
          C[(long)row * ldc + bn * 128 + wn + nt * 16 + ln15] = f2bf(v);
        }
      }
    }
  }
}

// ---------------- per-layer global max pool into g_pool[:, l*256:] ----------------
__global__ void pool_kernel(const u16* __restrict__ h, const int* __restrict__ gs,
                            float* __restrict__ g_pool, int l) {
  int g = blockIdx.x;
  int c = threadIdx.x & 255, ty = threadIdx.x >> 8;
  int beg = gs[g], end = gs[g + 1];
  float m = -INFINITY;
  for (int n = beg + ty; n < end; n += 4)
    m = fmaxf(m, bf2f(h[(long)n * 512 + c]));
  __shared__ float red[4][256];
  red[ty][c] = m;
  __syncthreads();
  if (ty == 0) {
    m = fmaxf(fmaxf(red[0][c], red[1][c]), fmaxf(red[2][c], red[3][c]));
    if (!(m > -INFINITY)) m = 0.f;
    g_pool[g * 1024 + l * 256 + c] = m;
  }
}

// ---------------- head (output dtype branches on flags[0]) ----------------
__global__ void fc1_kernel(const float* __restrict__ gp, const u16* __restrict__ W,
                           const u16* __restrict__ b, float* __restrict__ last_f,
                           void* __restrict__ outbuf, const int* __restrict__ flags) {
  int g = blockIdx.x, c = threadIdx.x;
  float acc = bf2f(b[c]);
  const float* gr = gp + g * 1024;
#pragma unroll 4
  for (int k = 0; k < 1024; k++)
    acc += gr[k] * bf2f(W[k * 256 + c]);
  acc = fmaxf(acc, 0.f);
  last_f[g * 256 + c] = acc;
  if (flags[0]) ((float*)outbuf)[4608 + g * 256 + c] = acc;
  else          ((u16*)outbuf)[4608 + g * 256 + c] = f2bf(acc);
}

__global__ void fc2_kernel(const float* __restrict__ last, const u16* __restrict__ W,
                           const u16* __restrict__ b, void* __restrict__ outbuf,
                           const int* __restrict__ flags) {
  int g = blockIdx.x, t = threadIdx.x;
  __shared__ float sv[18];
  __shared__ float sred[2];
  if (t < 18) {
    float acc = bf2f(b[t]);
    const float* lr = last + g * 256;
    for (int k = 0; k < 256; k++)
      acc += lr[k] * bf2f(W[k * 18 + t]);
    sv[t] = acc;
  }
  __syncthreads();
  if (t == 0) {
    float mx = sv[0];
    for (int i = 1; i < 18; i++) mx = fmaxf(mx, sv[i]);
    float s = 0.f;
    for (int i = 0; i < 18; i++) s += expf(sv[i] - mx);
    sred[0] = mx; sred[1] = logf(s);
  }
  __syncthreads();
  if (t < 18) {
    float raw = sv[t];
    float lsm = sv[t] - sred[0] - sred[1];
    if (flags[0]) {
      ((float*)outbuf)[g * 18 + t] = lsm;
      ((float*)outbuf)[2304 + g * 18 + t] = raw;
    } else {
      ((u16*)outbuf)[g * 18 + t] = f2bf(lsm);
      ((u16*)outbuf)[2304 + g * 18 + t] = f2bf(raw);
    }
  }
}

extern "C" void kernel_launch(void* const* d_in, const int* in_sizes, int n_in,
                              void* d_out, int out_size, void* d_ws, size_t ws_size,
                              hipStream_t stream) {
  (void)in_sizes; (void)n_in; (void)out_size; (void)ws_size;
  const void* x = d_in[0];
  const void* ei = d_in[1];
  const void* batch = d_in[2];
  const void *Wl[4], *bl[4], *Wr[4], *Wm[4], *bm[4];
  for (int l = 0; l < 4; l++) {
    Wl[l] = d_in[3 + l * 5 + 0];
    bl[l] = d_in[3 + l * 5 + 1];
    Wr[l] = d_in[3 + l * 5 + 2];
    Wm[l] = d_in[3 + l * 5 + 3];
    bm[l] = d_in[3 + l * 5 + 4];
  }
  const void* fc1W = d_in[23];
  const void* fc1b = d_in[24];
  const void* fc2W = d_in[25];
  const void* fc2b = d_in[26];

  char* ws = (char*)d_ws;
  size_t off = 0;
  auto alloc = [&](size_t bytes) -> void* {
    void* p = ws + off;
    off = (off + bytes + 255) & ~(size_t)255;
    return p;
  };
  int* flags   = (int*)alloc(16);
  int* row_ptr = (int*)alloc((NN + 1) * sizeof(int));
  int* cursor  = (int*)alloc(NN * sizeof(int));
  int* partial = (int*)alloc(NCHUNK * sizeof(int));
  int* col_src = (int*)alloc((size_t)EE * sizeof(int));
  int* src32   = (int*)alloc((size_t)EE * sizeof(int));
  int* dst32   = (int*)alloc((size_t)EE * sizeof(int));
  int* batch32 = (int*)alloc(NN * sizeof(int));
  int* gs      = (int*)alloc((GG + 1) * sizeof(int));
  u16* WcatT[4]; for (int l = 0; l < 4; l++) WcatT[l] = (u16*)alloc(256 * 512 * 2);
  u16* WmT[4];   for (int l = 0; l < 4; l++) WmT[l]   = (u16*)alloc(256 * 256 * 2);
  u16* bl_bf[4]; for (int l = 0; l < 4; l++) bl_bf[l] = (u16*)alloc(256 * 2);
  u16* bm_bf[4]; for (int l = 0; l < 4; l++) bm_bf[l] = (u16*)alloc(256 * 2);
  u16* fc1W_bf = (u16*)alloc(1024 * 256 * 2);
  u16* fc1b_bf = (u16*)alloc(256 * 2);
  u16* fc2W_bf = (u16*)alloc(256 * 18 * 2);
  u16* fc2b_bf = (u16*)alloc(18 * 2);
  u16* x_bf    = (u16*)alloc((size_t)NN * DF * 2);
  u16* Acat    = (u16*)alloc((size_t)NN * 512 * 2);
  u16* tmp     = (u16*)alloc((size_t)NN * 256 * 2);
  float* gpool = (float*)alloc(GG * 1024 * sizeof(float));
  float* lastf = (float*)alloc(GG * 256 * sizeof(float));

  hipMemsetAsync(flags, 0, 16, stream);
  detect_kernel<<<256, 256, 0, stream>>>((const u16*)x, (const unsigned*)ei, flags);

  ConvArgs CA; int blk = 0; int si = 0;
  auto addseg = [&](const void* s, u16* d, int n) {
    CA.s[si].src = s; CA.s[si].dst = d; CA.s[si].start_blk = blk; CA.s[si].n = n;
    blk += (n + 255) / 256; si++;
  };
  addseg(x, x_bf, NN * DF);
  addseg(fc1W, fc1W_bf, 1024 * 256);
  addseg(fc2W, fc2W_bf, 256 * 18);
  for (int l = 0; l < 4; l++) addseg(bl[l], bl_bf[l], 256);
  for (int l = 0; l < 4; l++) addseg(bm[l], bm_bf[l], 256);
  addseg(fc1b, fc1b_bf, 256);
  addseg(fc2b, fc2b_bf, 18);
  CA.nseg = si;
  conv_many<<<blk, 256, 0, stream>>>(CA, flags);
  conv_idx<<<(EE + 255) / 256, 256, 0, stream>>>(ei, batch, src32, dst32, batch32, flags);

  WPtrs P;
  for (int l = 0; l < 4; l++) {
    P.Wl[l] = Wl[l]; P.Wr[l] = Wr[l]; P.Wm[l] = Wm[l];
    P.WcatT[l] = WcatT[l]; P.WmT[l] = WmT[l];
  }
  prep_w_kernel<<<4096, 256, 0, stream>>>(P, flags);

  hipMemsetAsync(cursor, 0, NN * sizeof(int), stream);
  hist_kernel<<<(EE + 255) / 256, 256, 0, stream>>>(dst32, cursor, EE);
  chunk_sum_kernel<<<NCHUNK, 256, 0, stream>>>(cursor, partial, NN);
  scan_partial_kernel<<<1, 256, 0, stream>>>(partial, NCHUNK);
  write_rowptr_kernel<<<NCHUNK, 256, 0, stream>>>(cursor, partial, row_ptr, NN);
  scatter_kernel<<<(EE + 255) / 256, 256, 0, stream>>>(src32, dst32, cursor, col_src, EE);
  graph_start_kernel<<<1, 256, 0, stream>>>(batch32, gs, NN);

  int segblocks = (NN + 3) / 4;
  int gemmgrid = ((NN + 127) / 128) * 2;

  for (int l = 0; l < 4; l++) {
    if (l == 0) {
      segmax_kernel<2><<<segblocks, 256, 0, stream>>>(x_bf, DF, row_ptr, col_src,
                                                      Acat, 512, Acat + DF, NN);
    } else {
      segmax_kernel<4><<<segblocks, 256, 0, stream>>>(Acat + 256, 512, row_ptr, col_src,
                                                      Acat, 512, (u16*)nullptr, NN);
    }
    int K = (l == 0) ? 256 : 512;
    gemm_kernel<<<gemmgrid, 256, 0, stream>>>(Acat, 512, K, WcatT[l], bl_bf[l], tmp, 256, NN, 0);
    gemm_kernel<<<gemmgrid, 256, 0, stream>>>(tmp, 256, 256, WmT[l], bm_bf[l], Acat + 256, 512, NN, 1);
    pool_kernel<<<GG, 1024, 0, stream>>>(Acat + 256, gs, gpool, l);
  }

  fc1_kernel<<<GG, 256, 0, stream>>>(gpool, fc1W_bf, fc1b_bf, lastf, d_out, flags);
  fc2_kernel<<<GG, 64, 0, stream>>>(lastf, fc2W_bf, fc2b_bf, d_out, flags);
}